// Round 1
// 552.970 us; speedup vs baseline: 1.1784x; 1.1784x over previous
//
#include <hip/hip_runtime.h>

typedef __bf16 bf16;
typedef __attribute__((ext_vector_type(8))) __bf16 bf16x8;
typedef __attribute__((ext_vector_type(4))) float f32x4;

// ---------------------------------------------------------------- utilities

__device__ __forceinline__ unsigned short f2bf(float f) {
    union { float f; unsigned u; } v; v.f = f;
    unsigned r = v.u + 0x7FFFu + ((v.u >> 16) & 1u);   // RNE
    return (unsigned short)(r >> 16);
}

// Stage a 128-row x 64-bf16 (128 B/row) tile from global into LDS via
// global_load_lds width=16. 256 threads x 4 reps x 16 B = 16 KB.
// XOR swizzle: row r's global 16B chunk c lands at LDS chunk c ^ (r&7)
// (breaks the 16-way bank conflict of the plain layout; R2 measured 0
// SQ_LDS_BANK_CONFLICT with this scheme).
__device__ __forceinline__ void stage128x64(const bf16* g, int ld_elems,
                                            bf16* lds, int tid) {
    const char* gb = (const char*)g;
    const int ldb = ld_elems * 2;
#pragma unroll
    for (int r = 0; r < 4; ++r) {
        int lin = r * 256 + tid;          // 0..1023, lane-contiguous per wave
        int row = lin >> 3;               // 8 x 16B chunks per 128 B row
        int ch  = (lin & 7) ^ (row & 7);  // XOR swizzle
        __builtin_amdgcn_global_load_lds(
            (const __attribute__((address_space(1))) void*)(gb + (size_t)row * ldb + ch * 16),
            (__attribute__((address_space(3))) void*)(lds + lin * 8),
            16, 0, 0);
    }
}

// 128x128 tile step (4 waves 2x2), BK=64. Used by proj and scores.
__device__ __forceinline__ void mma_tile(const bf16* As, const bf16* Bs,
                                         int wm, int wn, int lane,
                                         f32x4 acc[4][4]) {
    const int lm = lane & 15;
    const int g  = lane >> 4;
#pragma unroll
    for (int ks = 0; ks < 2; ++ks) {
        const int c = ks * 4 + g;
        bf16x8 a[4], b[4];
#pragma unroll
        for (int t = 0; t < 4; ++t) {
            const int row = wm * 64 + t * 16 + lm;
            a[t] = *(const bf16x8*)(As + row * 64 + ((c ^ (row & 7)) << 3));
        }
#pragma unroll
        for (int t = 0; t < 4; ++t) {
            const int row = wn * 64 + t * 16 + lm;
            b[t] = *(const bf16x8*)(Bs + row * 64 + ((c ^ (row & 7)) << 3));
        }
#pragma unroll
        for (int i = 0; i < 4; ++i)
#pragma unroll
            for (int j = 0; j < 4; ++j)
                acc[i][j] = __builtin_amdgcn_mfma_f32_16x16x32_bf16(a[i], b[j], acc[i][j], 0, 0, 0);
    }
}

// ---------------------------------------------------------------- kernels

// fp32 -> bf16 for x, Wq, Wk, Wo. (Z no longer needs zeroing: scores writes
// it directly now.)
__global__ void convert_kernel(const float* __restrict__ x,  const float* __restrict__ Wq,
                               const float* __restrict__ Wk, const float* __restrict__ Wo,
                               unsigned short* xb, unsigned short* Wqb,
                               unsigned short* Wkb, unsigned short* Wob) {
    size_t i = ((size_t)blockIdx.x * 256 + threadIdx.x) * 4;
    const float* src; unsigned short* dst; size_t off;
    if      (i < 4194304) { src = x;  dst = xb;  off = i; }
    else if (i < 5242880) { src = Wq; dst = Wqb; off = i - 4194304; }
    else if (i < 6291456) { src = Wk; dst = Wkb; off = i - 5242880; }
    else                  { src = Wo; dst = Wob; off = i - 6291456; }
    float4 v = *(const float4*)(src + off);
    ushort4 o;
    o.x = f2bf(v.x); o.y = f2bf(v.y); o.z = f2bf(v.z); o.w = f2bf(v.w);
    *(ushort4*)(dst + off) = o;
}

// Q = Xb @ Wq^T + bq, K = Xb @ Wk^T + bk  (blockIdx.z selects Q or K).
__global__ __launch_bounds__(256) void proj_kernel(
        const bf16* __restrict__ X, const bf16* __restrict__ Wqb,
        const bf16* __restrict__ Wkb, const float* __restrict__ bq,
        const float* __restrict__ bk, unsigned short* Qb, unsigned short* Kb) {
    __shared__ bf16 As[128 * 64];
    __shared__ bf16 Bs[128 * 64];
    const int tid = threadIdx.x, wid = tid >> 6, lane = tid & 63;
    const int wm = wid >> 1, wn = wid & 1;
    const int n0 = blockIdx.x * 128, m0 = blockIdx.y * 128;
    const bf16*  W    = blockIdx.z ? Wkb : Wqb;
    const float* bias = blockIdx.z ? bk  : bq;
    unsigned short* Out = blockIdx.z ? Kb : Qb;

    f32x4 acc[4][4];
    const f32x4 z4 = {0.f, 0.f, 0.f, 0.f};
#pragma unroll
    for (int i = 0; i < 4; ++i)
#pragma unroll
        for (int j = 0; j < 4; ++j) acc[i][j] = z4;

    for (int kt = 0; kt < 16; ++kt) {
        stage128x64(X + (size_t)m0 * 1024 + kt * 64, 1024, As, tid);
        stage128x64(W + (size_t)n0 * 1024 + kt * 64, 1024, Bs, tid);
        __syncthreads();
        mma_tile(As, Bs, wm, wn, lane, acc);
        __syncthreads();
    }

    const int q = lane >> 4, lm = lane & 15;
#pragma unroll
    for (int j = 0; j < 4; ++j) {
        const int col = n0 + wn * 64 + j * 16 + lm;
        const float bc = bias[col];
#pragma unroll
        for (int i = 0; i < 4; ++i)
#pragma unroll
            for (int r = 0; r < 4; ++r) {
                const int row = m0 + wm * 64 + i * 16 + q * 4 + r;
                Out[(size_t)row * 1024 + col] = f2bf(acc[i][j][r] + bc);
            }
    }
}

// One block per (b, h, 128-row i-tile). Sweeps all 1024 keys in 8 chunks of
// 128 with a double-buffered K-tile (1 barrier/chunk; staging overlaps the
// exp/mask epilogue). Q-tile staged ONCE. Row sums accumulate in registers
// across the sweep -> Z written directly (no atomics, no pre-zeroing).
__global__ __launch_bounds__(256) void scores_kernel(
        const bf16* __restrict__ Qb, const bf16* __restrict__ Kb,
        const int* __restrict__ mask, unsigned short* Pun, float* Z) {
    __shared__ bf16 As[128 * 64];
    __shared__ bf16 Bs[2][128 * 64];
    __shared__ float Zs[2][128];
    const int tid = threadIdx.x, wid = tid >> 6, lane = tid & 63;
    const int wm = wid >> 1, wn = wid & 1;
    const int i0 = blockIdx.x * 128;
    const int h = blockIdx.y & 15, b = blockIdx.y >> 4;
    const int q = lane >> 4, lm = lane & 15;

    const bf16* Qh = Qb + ((size_t)(b * 1024 + i0)) * 1024 + h * 64;
    const bf16* Kh = Kb + ((size_t)(b * 1024)) * 1024 + h * 64;

    stage128x64(Qh, 1024, As, tid);
    stage128x64(Kh, 1024, Bs[0], tid);

    float rs[4][4];
#pragma unroll
    for (int i = 0; i < 4; ++i)
#pragma unroll
        for (int r = 0; r < 4; ++r) rs[i][r] = 0.f;

    for (int jt = 0; jt < 8; ++jt) {
        __syncthreads();   // Bs[jt&1] staged; all waves done reading Bs[(jt+1)&1]
        if (jt < 7)
            stage128x64(Kh + (size_t)(jt + 1) * 128 * 1024, 1024, Bs[(jt + 1) & 1], tid);

        f32x4 acc[4][4];
        const f32x4 z4 = {0.f, 0.f, 0.f, 0.f};
#pragma unroll
        for (int i = 0; i < 4; ++i)
#pragma unroll
            for (int j = 0; j < 4; ++j) acc[i][j] = z4;
        mma_tile(As, Bs[jt & 1], wm, wn, lane, acc);

#pragma unroll
        for (int i = 0; i < 4; ++i)
#pragma unroll
            for (int r = 0; r < 4; ++r) {
                const int ii = i0 + wm * 64 + i * 16 + q * 4 + r;
                const size_t mrow = (size_t)b * 16384 + (size_t)ii * 16 + h;
#pragma unroll
                for (int j = 0; j < 4; ++j) {
                    const int jj = jt * 128 + wn * 64 + j * 16 + lm;
                    const float s = acc[i][j][r] * 0.125f;
                    const int mk = mask[((size_t)b * 1024 + ii) * 1024 + jj];
                    const float p = mk ? __expf(s) : 0.f;
                    Pun[mrow * 1024 + jj] = f2bf(p);
                    rs[i][r] += p;
                }
            }
    }

    // reduce row sums: 16 lanes -> wn pair via LDS -> global Z
#pragma unroll
    for (int i = 0; i < 4; ++i)
#pragma unroll
        for (int r = 0; r < 4; ++r) {
            float v = rs[i][r];
            for (int off = 1; off < 16; off <<= 1) v += __shfl_xor(v, off, 16);
            if (lm == 0) Zs[wn][wm * 64 + i * 16 + q * 4 + r] = v;
        }
    __syncthreads();
    if (tid < 128) {
        const size_t m = (size_t)b * 16384 + (size_t)(i0 + tid) * 16 + h;
        Z[m] = Zs[0][tid] + Zs[1][tid];
    }
}

// out = (Pun @ Wo^T) / Z[m] + bo[e].  M=65536, N=1024, K=1024.
// 256x128 tile, 4 waves: wave w owns rows w*64..+63 x all 128 cols
// (acc 4x8). Per K-step: 256 MFMA vs 96 ds_read_b128 -> MFMA-bound ratio.
//
// R3: latency-bound fix (MfmaUtil 19 / HBM 35% / Occ 11.6%):
//  (a) XCD-disjoint slab decode: hardware round-robins consecutive
//      blockIdx.x across the 8 XCDs, so with n in the low bits the 8 blocks
//      sharing one 512 KB A-panel hit 8 DIFFERENT L2s (FETCH was 4x ideal).
//      Now xcd = bx&7 owns m-tiles [xcd*32, xcd*32+32), n fastest within the
//      slab -> panel-sharers are consecutive blocks on ONE XCD; Pun slabs
//      disjoint across XCDs -> each byte of Pun fetched ~once.
//  (b) __launch_bounds__(256,3): VGPR was 172, 2 over the 170 needed for
//      3 waves/SIMD; LDS 48 KB already allows 3 blocks/CU. Inner loop
//      restructured (one B-frag live at a time, not b[8]) so the live set
//      (acc 128 + a 16 + b 4 + addr) fits 170 without inner-loop spills.
__global__ __launch_bounds__(256, 3) void out_gemm_kernel(
        const bf16* __restrict__ Pun, const bf16* __restrict__ Wob,
        const float* __restrict__ Z, const float* __restrict__ bo,
        float* __restrict__ out) {
    __shared__ bf16 As[256 * 64];
    __shared__ bf16 Bs[128 * 64];
    const int tid = threadIdx.x, w = tid >> 6, lane = tid & 63;
    const int lm = lane & 15, g = lane >> 4;

    // XCD-aware decode (2048 blocks = 8 XCDs x 32 m-tiles x 8 n-tiles)
    const int bx  = blockIdx.x;
    const int xcd = bx & 7;
    const int j   = bx >> 3;
    const int m0  = (xcd * 32 + (j >> 3)) * 256;
    const int n0  = (j & 7) * 128;

    f32x4 acc[4][8];
    const f32x4 z4 = {0.f, 0.f, 0.f, 0.f};
#pragma unroll
    for (int i = 0; i < 4; ++i)
#pragma unroll
        for (int jj = 0; jj < 8; ++jj) acc[i][jj] = z4;

    for (int kt = 0; kt < 16; ++kt) {
        stage128x64(Pun + (size_t)m0 * 1024 + kt * 64, 1024, As, tid);
        stage128x64(Pun + (size_t)(m0 + 128) * 1024 + kt * 64, 1024, As + 128 * 64, tid);
        stage128x64(Wob + (size_t)n0 * 1024 + kt * 64, 1024, Bs, tid);
        __syncthreads();
#pragma unroll
        for (int ks = 0; ks < 2; ++ks) {
            const int c = ks * 4 + g;
            bf16x8 a[4];
#pragma unroll
            for (int t = 0; t < 4; ++t) {
                const int row = w * 64 + t * 16 + lm;
                a[t] = *(const bf16x8*)(As + row * 64 + ((c ^ (row & 7)) << 3));
            }
#pragma unroll
            for (int jj = 0; jj < 8; ++jj) {
                const int row = jj * 16 + lm;
                const bf16x8 b = *(const bf16x8*)(Bs + row * 64 + ((c ^ (row & 7)) << 3));
#pragma unroll
                for (int i = 0; i < 4; ++i)
                    acc[i][jj] = __builtin_amdgcn_mfma_f32_16x16x32_bf16(a[i], b, acc[i][jj], 0, 0, 0);
            }
        }
        __syncthreads();
    }

#pragma unroll
    for (int i = 0; i < 4; ++i)
#pragma unroll
        for (int r = 0; r < 4; ++r) {
            const int row = m0 + w * 64 + i * 16 + g * 4 + r;
            const float zi = 1.0f / Z[row];
#pragma unroll
            for (int jj = 0; jj < 8; ++jj) {
                const int col = n0 + jj * 16 + lm;
                out[(size_t)row * 1024 + col] = acc[i][jj][r] * zi + bo[col];
            }
        }
}

// ---------------------------------------------------------------- launch

extern "C" void kernel_launch(void* const* d_in, const int* in_sizes, int n_in,
                              void* d_out, int out_size, void* d_ws, size_t ws_size,
                              hipStream_t stream) {
    (void)in_sizes; (void)n_in; (void)out_size; (void)ws_size;
    const float* x    = (const float*)d_in[0];
    const int*   mask = (const int*)d_in[1];
    const float* Wq   = (const float*)d_in[2];
    const float* bq   = (const float*)d_in[3];
    const float* Wk   = (const float*)d_in[4];
    const float* bk   = (const float*)d_in[5];
    // d_in[6]=Wv, d_in[7]=bv: computed-then-discarded in reference; skipped.
    const float* Wo   = (const float*)d_in[8];
    const float* bo   = (const float*)d_in[9];

    char* ws = (char*)d_ws;
    bf16*  xb  = (bf16*)(ws);                    //  8 MB  x bf16
    bf16*  Wqb = (bf16*)(ws + 8388608);          //  2 MB
    bf16*  Wkb = (bf16*)(ws + 10485760);         //  2 MB
    bf16*  Wob = (bf16*)(ws + 12582912);         //  2 MB
    bf16*  Qb  = (bf16*)(ws + 14680064);         //  8 MB
    bf16*  Kb  = (bf16*)(ws + 23068672);         //  8 MB
    float* Z   = (float*)(ws + 31457280);        // 256 KB
    bf16*  Pun = (bf16*)(ws + 31981568);         // 128 MB (end ~158.5 MB)

    convert_kernel<<<7168, 256, 0, stream>>>(x, Wq, Wk, Wo,
        (unsigned short*)xb, (unsigned short*)Wqb, (unsigned short*)Wkb,
        (unsigned short*)Wob);
    proj_kernel<<<dim3(8, 32, 2), 256, 0, stream>>>(xb, Wqb, Wkb, bq, bk,
        (unsigned short*)Qb, (unsigned short*)Kb);
    scores_kernel<<<dim3(8, 64), 256, 0, stream>>>(Qb, Kb, mask,
        (unsigned short*)Pun, Z);
    out_gemm_kernel<<<2048, 256, 0, stream>>>(Pun, Wob, Z, bo, (float*)d_out);
}

// Round 3
// 547.450 us; speedup vs baseline: 1.1903x; 1.0101x over previous
//
#include <hip/hip_runtime.h>

typedef __bf16 bf16;
typedef __attribute__((ext_vector_type(8))) __bf16 bf16x8;
typedef __attribute__((ext_vector_type(4))) float f32x4;

// ---------------------------------------------------------------- utilities

__device__ __forceinline__ unsigned short f2bf(float f) {
    union { float f; unsigned u; } v; v.f = f;
    unsigned r = v.u + 0x7FFFu + ((v.u >> 16) & 1u);   // RNE
    return (unsigned short)(r >> 16);
}

// Stage a 128-row x 64-bf16 (128 B/row) tile from global into LDS via
// global_load_lds width=16. 256 threads x 4 reps x 16 B = 16 KB.
// XOR swizzle: row r's global 16B chunk c lands at LDS chunk c ^ (r&7).
__device__ __forceinline__ void stage128x64(const bf16* g, int ld_elems,
                                            bf16* lds, int tid) {
    const char* gb = (const char*)g;
    const int ldb = ld_elems * 2;
#pragma unroll
    for (int r = 0; r < 4; ++r) {
        int lin = r * 256 + tid;          // 0..1023, lane-contiguous per wave
        int row = lin >> 3;               // 8 x 16B chunks per 128 B row
        int ch  = (lin & 7) ^ (row & 7);  // XOR swizzle
        __builtin_amdgcn_global_load_lds(
            (const __attribute__((address_space(1))) void*)(gb + (size_t)row * ldb + ch * 16),
            (__attribute__((address_space(3))) void*)(lds + lin * 8),
            16, 0, 0);
    }
}

// Same tile shape, 512-thread block variant (2 loads/thread).
// Row stride hardcoded 1024 elems (both Pun and Wob).
__device__ __forceinline__ void stage_half512(const bf16* g, bf16* lds, int tid) {
    const char* gb = (const char*)g;
#pragma unroll
    for (int r = 0; r < 2; ++r) {
        int lin = r * 512 + tid;          // 0..1023
        int row = lin >> 3;
        int ch  = (lin & 7) ^ (row & 7);
        __builtin_amdgcn_global_load_lds(
            (const __attribute__((address_space(1))) void*)(gb + (size_t)row * 2048 + ch * 16),
            (__attribute__((address_space(3))) void*)(lds + lin * 8),
            16, 0, 0);
    }
}

// 128x128 tile step (4 waves 2x2), BK=64. Used by proj and scores.
__device__ __forceinline__ void mma_tile(const bf16* As, const bf16* Bs,
                                         int wm, int wn, int lane,
                                         f32x4 acc[4][4]) {
    const int lm = lane & 15;
    const int g  = lane >> 4;
#pragma unroll
    for (int ks = 0; ks < 2; ++ks) {
        const int c = ks * 4 + g;
        bf16x8 a[4], b[4];
#pragma unroll
        for (int t = 0; t < 4; ++t) {
            const int row = wm * 64 + t * 16 + lm;
            a[t] = *(const bf16x8*)(As + row * 64 + ((c ^ (row & 7)) << 3));
        }
#pragma unroll
        for (int t = 0; t < 4; ++t) {
            const int row = wn * 64 + t * 16 + lm;
            b[t] = *(const bf16x8*)(Bs + row * 64 + ((c ^ (row & 7)) << 3));
        }
#pragma unroll
        for (int i = 0; i < 4; ++i)
#pragma unroll
            for (int j = 0; j < 4; ++j)
                acc[i][j] = __builtin_amdgcn_mfma_f32_16x16x32_bf16(a[i], b[j], acc[i][j], 0, 0, 0);
    }
}

// ---------------------------------------------------------------- kernels

// fp32 -> bf16 for x, Wq, Wk, Wo.
__global__ void convert_kernel(const float* __restrict__ x,  const float* __restrict__ Wq,
                               const float* __restrict__ Wk, const float* __restrict__ Wo,
                               unsigned short* xb, unsigned short* Wqb,
                               unsigned short* Wkb, unsigned short* Wob) {
    size_t i = ((size_t)blockIdx.x * 256 + threadIdx.x) * 4;
    const float* src; unsigned short* dst; size_t off;
    if      (i < 4194304) { src = x;  dst = xb;  off = i; }
    else if (i < 5242880) { src = Wq; dst = Wqb; off = i - 4194304; }
    else if (i < 6291456) { src = Wk; dst = Wkb; off = i - 5242880; }
    else                  { src = Wo; dst = Wob; off = i - 6291456; }
    float4 v = *(const float4*)(src + off);
    ushort4 o;
    o.x = f2bf(v.x); o.y = f2bf(v.y); o.z = f2bf(v.z); o.w = f2bf(v.w);
    *(ushort4*)(dst + off) = o;
}

// Q = Xb @ Wq^T + bq, K = Xb @ Wk^T + bk  (blockIdx.z selects Q or K).
__global__ __launch_bounds__(256) void proj_kernel(
        const bf16* __restrict__ X, const bf16* __restrict__ Wqb,
        const bf16* __restrict__ Wkb, const float* __restrict__ bq,
        const float* __restrict__ bk, unsigned short* Qb, unsigned short* Kb) {
    __shared__ bf16 As[128 * 64];
    __shared__ bf16 Bs[128 * 64];
    const int tid = threadIdx.x, wid = tid >> 6, lane = tid & 63;
    const int wm = wid >> 1, wn = wid & 1;
    const int n0 = blockIdx.x * 128, m0 = blockIdx.y * 128;
    const bf16*  W    = blockIdx.z ? Wkb : Wqb;
    const float* bias = blockIdx.z ? bk  : bq;
    unsigned short* Out = blockIdx.z ? Kb : Qb;

    f32x4 acc[4][4];
    const f32x4 z4 = {0.f, 0.f, 0.f, 0.f};
#pragma unroll
    for (int i = 0; i < 4; ++i)
#pragma unroll
        for (int j = 0; j < 4; ++j) acc[i][j] = z4;

    for (int kt = 0; kt < 16; ++kt) {
        stage128x64(X + (size_t)m0 * 1024 + kt * 64, 1024, As, tid);
        stage128x64(W + (size_t)n0 * 1024 + kt * 64, 1024, Bs, tid);
        __syncthreads();
        mma_tile(As, Bs, wm, wn, lane, acc);
        __syncthreads();
    }

    const int q = lane >> 4, lm = lane & 15;
#pragma unroll
    for (int j = 0; j < 4; ++j) {
        const int col = n0 + wn * 64 + j * 16 + lm;
        const float bc = bias[col];
#pragma unroll
        for (int i = 0; i < 4; ++i)
#pragma unroll
            for (int r = 0; r < 4; ++r) {
                const int row = m0 + wm * 64 + i * 16 + q * 4 + r;
                Out[(size_t)row * 1024 + col] = f2bf(acc[i][j][r] + bc);
            }
    }
}

// One block per (b, h, 128-row i-tile). Sweeps all 1024 keys in 8 chunks of
// 128 with a double-buffered K-tile. Q-tile staged ONCE. Row sums accumulate
// in registers -> Z written directly.
__global__ __launch_bounds__(256) void scores_kernel(
        const bf16* __restrict__ Qb, const bf16* __restrict__ Kb,
        const int* __restrict__ mask, unsigned short* Pun, float* Z) {
    __shared__ bf16 As[128 * 64];
    __shared__ bf16 Bs[2][128 * 64];
    __shared__ float Zs[2][128];
    const int tid = threadIdx.x, wid = tid >> 6, lane = tid & 63;
    const int wm = wid >> 1, wn = wid & 1;
    const int i0 = blockIdx.x * 128;
    const int h = blockIdx.y & 15, b = blockIdx.y >> 4;
    const int q = lane >> 4, lm = lane & 15;

    const bf16* Qh = Qb + ((size_t)(b * 1024 + i0)) * 1024 + h * 64;
    const bf16* Kh = Kb + ((size_t)(b * 1024)) * 1024 + h * 64;

    stage128x64(Qh, 1024, As, tid);
    stage128x64(Kh, 1024, Bs[0], tid);

    float rs[4][4];
#pragma unroll
    for (int i = 0; i < 4; ++i)
#pragma unroll
        for (int r = 0; r < 4; ++r) rs[i][r] = 0.f;

    for (int jt = 0; jt < 8; ++jt) {
        __syncthreads();   // Bs[jt&1] staged; all waves done reading Bs[(jt+1)&1]
        if (jt < 7)
            stage128x64(Kh + (size_t)(jt + 1) * 128 * 1024, 1024, Bs[(jt + 1) & 1], tid);

        f32x4 acc[4][4];
        const f32x4 z4 = {0.f, 0.f, 0.f, 0.f};
#pragma unroll
        for (int i = 0; i < 4; ++i)
#pragma unroll
            for (int j = 0; j < 4; ++j) acc[i][j] = z4;
        mma_tile(As, Bs[jt & 1], wm, wn, lane, acc);

#pragma unroll
        for (int i = 0; i < 4; ++i)
#pragma unroll
            for (int r = 0; r < 4; ++r) {
                const int ii = i0 + wm * 64 + i * 16 + q * 4 + r;
                const size_t mrow = (size_t)b * 16384 + (size_t)ii * 16 + h;
#pragma unroll
                for (int j = 0; j < 4; ++j) {
                    const int jj = jt * 128 + wn * 64 + j * 16 + lm;
                    const float s = acc[i][j][r] * 0.125f;
                    const int mk = mask[((size_t)b * 1024 + ii) * 1024 + jj];
                    const float p = mk ? __expf(s) : 0.f;
                    Pun[mrow * 1024 + jj] = f2bf(p);
                    rs[i][r] += p;
                }
            }
    }

#pragma unroll
    for (int i = 0; i < 4; ++i)
#pragma unroll
        for (int r = 0; r < 4; ++r) {
            float v = rs[i][r];
            for (int off = 1; off < 16; off <<= 1) v += __shfl_xor(v, off, 16);
            if (lm == 0) Zs[wn][wm * 64 + i * 16 + q * 4 + r] = v;
        }
    __syncthreads();
    if (tid < 128) {
        const size_t m = (size_t)b * 16384 + (size_t)(i0 + tid) * 16 + h;
        Z[m] = Zs[0][tid] + Zs[1][tid];
    }
}

// out = (Pun @ Wo^T) / Z[m] + bo[e].  M=65536, N=1024, K=1024.
//
// R4 (resubmit of R2's 8-phase; R2 bench died of container failure — error
// was container-health, not pytest/absmax; ledger+barriers+bounds re-audited,
// no kernel-side fault found):
// 8-phase 256x256 schedule (T3+T4 counted vmcnt + T5 setprio). 512 thr =
// 8 waves (2M x 4N), per-wave 128x64 output (acc[8][4]), BK=64, LDS 128 KiB
// (2 dbuf x {A,B} x 2 halves of 128x64). Phases P0-P3 compute even tile t
// (buf0), P4-P7 odd tile t+1 (buf1); each phase stages ONE half-tile:
//   P0:B1(t+1) P1:A0(t+1) P2:A1(t+1) P3:B0(t+2)
//   P4:B1(t+2) P5:A0(t+2) P6:A1(t+2) P7:B0(t+3)
// Every stage issue is >=1 barrier after the last ds_read of the half it
// overwrites (A halves free after P3/P7, B halves after P2/P6). Gates:
// vmcnt(2) before bar2 of P3 and P7 only (retires the 8 oldest = exactly the
// 4 half-tiles the next 4 phases read; newest stays in flight). Never drains
// to 0 except the final-iteration P3.
__global__ __launch_bounds__(512, 2) void out_gemm_kernel(
        const bf16* __restrict__ Pun, const bf16* __restrict__ Wob,
        const float* __restrict__ Z, const float* __restrict__ bo,
        float* __restrict__ out) {
    __shared__ bf16 As[2][2][128 * 64];   // [buf][half][...]
    __shared__ bf16 Bs[2][2][128 * 64];
    const int tid = threadIdx.x, wid = tid >> 6, lane = tid & 63;
    const int wm = wid >> 2, wn = wid & 3;
    const int lm = lane & 15, g = lane >> 4;

    // XCD-disjoint decode: 1024 blocks = 8 XCDs x 32 m-tiles x 4 n-tiles
    const int bx = blockIdx.x, xcd = bx & 7, j = bx >> 3;
    const int m0 = (xcd * 32 + (j >> 2)) * 256;
    const int n0 = (j & 3) * 256;
    const bf16* Apan = Pun + (size_t)m0 * 1024;
    const bf16* Bpan = Wob + (size_t)n0 * 1024;

    f32x4 acc[8][4];
    const f32x4 z4 = {0.f, 0.f, 0.f, 0.f};
#pragma unroll
    for (int mi = 0; mi < 8; ++mi)
#pragma unroll
        for (int nj = 0; nj < 4; ++nj) acc[mi][nj] = z4;

    // prologue: B0(0) B1(0) A0(0) A1(0) B0(1); wait tile 0 landed (8 oldest).
    stage_half512(Bpan,                 Bs[0][0], tid);
    stage_half512(Bpan + 128 * 1024,    Bs[0][1], tid);
    stage_half512(Apan,                 As[0][0], tid);
    stage_half512(Apan + 128 * 1024,    As[0][1], tid);
    stage_half512(Bpan + 64,            Bs[1][0], tid);
    asm volatile("s_waitcnt vmcnt(2)" ::: "memory");
    __builtin_amdgcn_s_barrier();
    __builtin_amdgcn_sched_barrier(0);

    bf16x8 b[4];   // B fragments persist across the mhalf pair of phases

#define MFMA16(MH)                                                            \
    _Pragma("unroll")                                                         \
    for (int mi = 0; mi < 4; ++mi)                                            \
      _Pragma("unroll")                                                       \
      for (int nj = 0; nj < 4; ++nj)                                          \
        acc[(MH) * 4 + mi][nj] = __builtin_amdgcn_mfma_f32_16x16x32_bf16(     \
            a[mi], b[nj], acc[(MH) * 4 + mi][nj], 0, 0, 0);

#define PHASE(BUF, MH, KS, RB, STAGE, GATE)                                   \
  {                                                                           \
    const int cs = ((((KS) * 4) + g) ^ (lm & 7)) << 3;                        \
    const bf16* pA = &As[BUF][wm][((MH) * 64 + lm) * 64] + cs;                \
    bf16x8 a[4];                                                              \
    _Pragma("unroll")                                                         \
    for (int mi = 0; mi < 4; ++mi)                                            \
      a[mi] = *(const bf16x8*)(pA + mi * 16 * 64);                            \
    if (RB) {                                                                 \
      const bf16* pB = &Bs[BUF][wn >> 1][((wn & 1) * 64 + lm) * 64] + cs;     \
      _Pragma("unroll")                                                       \
      for (int nj = 0; nj < 4; ++nj)                                          \
        b[nj] = *(const bf16x8*)(pB + nj * 16 * 64);                          \
    }                                                                         \
    STAGE;                                                                    \
    __builtin_amdgcn_s_barrier();                                             \
    asm volatile("s_waitcnt lgkmcnt(0)" ::: "memory");                        \
    __builtin_amdgcn_sched_barrier(0);                                        \
    __builtin_amdgcn_s_setprio(1);                                            \
    MFMA16(MH);                                                               \
    __builtin_amdgcn_s_setprio(0);                                            \
    __builtin_amdgcn_sched_barrier(0);                                        \
    GATE;                                                                     \
    __builtin_amdgcn_s_barrier();                                             \
    __builtin_amdgcn_sched_barrier(0);                                        \
  }

#pragma unroll 1
    for (int t = 0; t < 16; t += 2) {
        const bool more = (t < 14);
        // P0: tile t, mhalf0, ks0, read B@ks0; stage B1(t+1)
        PHASE(0, 0, 0, true,
              stage_half512(Bpan + 128 * 1024 + (t + 1) * 64, Bs[1][1], tid), )
        // P1: tile t, mhalf1, ks0; stage A0(t+1)
        PHASE(0, 1, 0, false,
              stage_half512(Apan + (t + 1) * 64, As[1][0], tid), )
        // P2: tile t, mhalf0, ks1, read B@ks1; stage A1(t+1)
        PHASE(0, 0, 1, true,
              stage_half512(Apan + 128 * 1024 + (t + 1) * 64, As[1][1], tid), )
        // P3: tile t, mhalf1, ks1; stage B0(t+2); GATE for tile t+1 reads
        PHASE(0, 1, 1, false,
              if (more) stage_half512(Bpan + (t + 2) * 64, Bs[0][0], tid),
              if (more) { asm volatile("s_waitcnt vmcnt(2)" ::: "memory"); }
              else      { asm volatile("s_waitcnt vmcnt(0)" ::: "memory"); } )
        // P4: tile t+1, mhalf0, ks0; stage B1(t+2)
        PHASE(1, 0, 0, true,
              if (more) stage_half512(Bpan + 128 * 1024 + (t + 2) * 64, Bs[0][1], tid), )
        // P5: tile t+1, mhalf1, ks0; stage A0(t+2)
        PHASE(1, 1, 0, false,
              if (more) stage_half512(Apan + (t + 2) * 64, As[0][0], tid), )
        // P6: tile t+1, mhalf0, ks1; stage A1(t+2)
        PHASE(1, 0, 1, true,
              if (more) stage_half512(Apan + 128 * 1024 + (t + 2) * 64, As[0][1], tid), )
        // P7: tile t+1, mhalf1, ks1; stage B0(t+3); GATE for tile t+2 reads
        PHASE(1, 1, 1, false,
              if (more) stage_half512(Bpan + (t + 3) * 64, Bs[1][0], tid),
              if (more) { asm volatile("s_waitcnt vmcnt(2)" ::: "memory"); } )
    }
#undef PHASE
#undef MFMA16

    // epilogue: acc -> out with 1/Z and bias (no LDS use, no sync needed)
#pragma unroll
    for (int mi = 0; mi < 8; ++mi) {
#pragma unroll
        for (int r = 0; r < 4; ++r) {
            const int row = m0 + wm * 128 + mi * 16 + g * 4 + r;
            const float zi = 1.0f / Z[row];
#pragma unroll
            for (int nj = 0; nj < 4; ++nj) {
                const int col = n0 + wn * 64 + nj * 16 + lm;
                out[(size_t)row * 1024 + col] = acc[mi][nj][r] * zi + bo[col];
            }
        }
    }
}

// ---------------------------------------------------------------- launch

extern "C" void kernel_launch(void* const* d_in, const int* in_sizes, int n_in,
                              void* d_out, int out_size, void* d_ws, size_t ws_size,
                              hipStream_t stream) {
    (void)in_sizes; (void)n_in; (void)out_size; (void)ws_size;
    const float* x    = (const float*)d_in[0];
    const int*   mask = (const int*)d_in[1];
    const float* Wq   = (const float*)d_in[2];
    const float* bq   = (const float*)d_in[3];
    const float* Wk   = (const float*)d_in[4];
    const float* bk   = (const float*)d_in[5];
    // d_in[6]=Wv, d_in[7]=bv: computed-then-discarded in reference; skipped.
    const float* Wo   = (const float*)d_in[8];
    const float* bo   = (const float*)d_in[9];

    char* ws = (char*)d_ws;
    bf16*  xb  = (bf16*)(ws);                    //  8 MB  x bf16
    bf16*  Wqb = (bf16*)(ws + 8388608);          //  2 MB
    bf16*  Wkb = (bf16*)(ws + 10485760);         //  2 MB
    bf16*  Wob = (bf16*)(ws + 12582912);         //  2 MB
    bf16*  Qb  = (bf16*)(ws + 14680064);         //  8 MB
    bf16*  Kb  = (bf16*)(ws + 23068672);         //  8 MB
    float* Z   = (float*)(ws + 31457280);        // 256 KB
    bf16*  Pun = (bf16*)(ws + 31981568);         // 128 MB (end ~158.5 MB)

    convert_kernel<<<7168, 256, 0, stream>>>(x, Wq, Wk, Wo,
        (unsigned short*)xb, (unsigned short*)Wqb, (unsigned short*)Wkb,
        (unsigned short*)Wob);
    proj_kernel<<<dim3(8, 32, 2), 256, 0, stream>>>(xb, Wqb, Wkb, bq, bk,
        (unsigned short*)Qb, (unsigned short*)Kb);
    scores_kernel<<<dim3(8, 64), 256, 0, stream>>>(Qb, Kb, mask,
        (unsigned short*)Pun, Z);
    out_gemm_kernel<<<1024, 512, 0, stream>>>(Pun, Wob, Z, bo, (float*)d_out);
}

// Round 4
// 545.892 us; speedup vs baseline: 1.1937x; 1.0029x over previous
//
#include <hip/hip_runtime.h>

typedef __bf16 bf16;
typedef __attribute__((ext_vector_type(8))) __bf16 bf16x8;
typedef __attribute__((ext_vector_type(4))) float f32x4;

// ---------------------------------------------------------------- utilities

__device__ __forceinline__ unsigned short f2bf(float f) {
    union { float f; unsigned u; } v; v.f = f;
    unsigned r = v.u + 0x7FFFu + ((v.u >> 16) & 1u);   // RNE
    return (unsigned short)(r >> 16);
}

// Stage a 128-row x 64-bf16 (128 B/row) tile from global into LDS via
// global_load_lds width=16. 256 threads x 4 reps x 16 B = 16 KB.
// XOR swizzle: row r's global 16B chunk c lands at LDS chunk c ^ (r&7).
__device__ __forceinline__ void stage128x64(const bf16* g, int ld_elems,
                                            bf16* lds, int tid) {
    const char* gb = (const char*)g;
    const int ldb = ld_elems * 2;
#pragma unroll
    for (int r = 0; r < 4; ++r) {
        int lin = r * 256 + tid;          // 0..1023, lane-contiguous per wave
        int row = lin >> 3;               // 8 x 16B chunks per 128 B row
        int ch  = (lin & 7) ^ (row & 7);  // XOR swizzle
        __builtin_amdgcn_global_load_lds(
            (const __attribute__((address_space(1))) void*)(gb + (size_t)row * ldb + ch * 16),
            (__attribute__((address_space(3))) void*)(lds + lin * 8),
            16, 0, 0);
    }
}

// Same tile shape, 512-thread block variant (2 loads/thread).
// Row stride hardcoded 1024 elems (both Pun and Wob).
__device__ __forceinline__ void stage_half512(const bf16* g, bf16* lds, int tid) {
    const char* gb = (const char*)g;
#pragma unroll
    for (int r = 0; r < 2; ++r) {
        int lin = r * 512 + tid;          // 0..1023
        int row = lin >> 3;
        int ch  = (lin & 7) ^ (row & 7);
        __builtin_amdgcn_global_load_lds(
            (const __attribute__((address_space(1))) void*)(gb + (size_t)row * 2048 + ch * 16),
            (__attribute__((address_space(3))) void*)(lds + lin * 8),
            16, 0, 0);
    }
}

// 128x128 tile step (4 waves 2x2), BK=64. Used by proj and scores.
__device__ __forceinline__ void mma_tile(const bf16* As, const bf16* Bs,
                                         int wm, int wn, int lane,
                                         f32x4 acc[4][4]) {
    const int lm = lane & 15;
    const int g  = lane >> 4;
#pragma unroll
    for (int ks = 0; ks < 2; ++ks) {
        const int c = ks * 4 + g;
        bf16x8 a[4], b[4];
#pragma unroll
        for (int t = 0; t < 4; ++t) {
            const int row = wm * 64 + t * 16 + lm;
            a[t] = *(const bf16x8*)(As + row * 64 + ((c ^ (row & 7)) << 3));
        }
#pragma unroll
        for (int t = 0; t < 4; ++t) {
            const int row = wn * 64 + t * 16 + lm;
            b[t] = *(const bf16x8*)(Bs + row * 64 + ((c ^ (row & 7)) << 3));
        }
#pragma unroll
        for (int i = 0; i < 4; ++i)
#pragma unroll
            for (int j = 0; j < 4; ++j)
                acc[i][j] = __builtin_amdgcn_mfma_f32_16x16x32_bf16(a[i], b[j], acc[i][j], 0, 0, 0);
    }
}

// ---------------------------------------------------------------- kernels

// fp32 -> bf16 for x, Wq, Wk, Wo.
__global__ void convert_kernel(const float* __restrict__ x,  const float* __restrict__ Wq,
                               const float* __restrict__ Wk, const float* __restrict__ Wo,
                               unsigned short* xb, unsigned short* Wqb,
                               unsigned short* Wkb, unsigned short* Wob) {
    size_t i = ((size_t)blockIdx.x * 256 + threadIdx.x) * 4;
    const float* src; unsigned short* dst; size_t off;
    if      (i < 4194304) { src = x;  dst = xb;  off = i; }
    else if (i < 5242880) { src = Wq; dst = Wqb; off = i - 4194304; }
    else if (i < 6291456) { src = Wk; dst = Wkb; off = i - 5242880; }
    else                  { src = Wo; dst = Wob; off = i - 6291456; }
    float4 v = *(const float4*)(src + off);
    ushort4 o;
    o.x = f2bf(v.x); o.y = f2bf(v.y); o.z = f2bf(v.z); o.w = f2bf(v.w);
    *(ushort4*)(dst + off) = o;
}

// Q = Xb @ Wq^T + bq, K = Xb @ Wk^T + bk  (blockIdx.z selects Q or K).
__global__ __launch_bounds__(256) void proj_kernel(
        const bf16* __restrict__ X, const bf16* __restrict__ Wqb,
        const bf16* __restrict__ Wkb, const float* __restrict__ bq,
        const float* __restrict__ bk, unsigned short* Qb, unsigned short* Kb) {
    __shared__ bf16 As[128 * 64];
    __shared__ bf16 Bs[128 * 64];
    const int tid = threadIdx.x, wid = tid >> 6, lane = tid & 63;
    const int wm = wid >> 1, wn = wid & 1;
    const int n0 = blockIdx.x * 128, m0 = blockIdx.y * 128;
    const bf16*  W    = blockIdx.z ? Wkb : Wqb;
    const float* bias = blockIdx.z ? bk  : bq;
    unsigned short* Out = blockIdx.z ? Kb : Qb;

    f32x4 acc[4][4];
    const f32x4 z4 = {0.f, 0.f, 0.f, 0.f};
#pragma unroll
    for (int i = 0; i < 4; ++i)
#pragma unroll
        for (int j = 0; j < 4; ++j) acc[i][j] = z4;

    for (int kt = 0; kt < 16; ++kt) {
        stage128x64(X + (size_t)m0 * 1024 + kt * 64, 1024, As, tid);
        stage128x64(W + (size_t)n0 * 1024 + kt * 64, 1024, Bs, tid);
        __syncthreads();
        mma_tile(As, Bs, wm, wn, lane, acc);
        __syncthreads();
    }

    const int q = lane >> 4, lm = lane & 15;
#pragma unroll
    for (int j = 0; j < 4; ++j) {
        const int col = n0 + wn * 64 + j * 16 + lm;
        const float bc = bias[col];
#pragma unroll
        for (int i = 0; i < 4; ++i)
#pragma unroll
            for (int r = 0; r < 4; ++r) {
                const int row = m0 + wm * 64 + i * 16 + q * 4 + r;
                Out[(size_t)row * 1024 + col] = f2bf(acc[i][j][r] + bc);
            }
    }
}

// One block per (b, h, 128-row i-tile). Sweeps all 1024 keys in 8 chunks of
// 128 with a double-buffered K-tile. Q-tile staged ONCE. Row sums accumulate
// in registers -> Z written directly.
__global__ __launch_bounds__(256) void scores_kernel(
        const bf16* __restrict__ Qb, const bf16* __restrict__ Kb,
        const int* __restrict__ mask, unsigned short* Pun, float* Z) {
    __shared__ bf16 As[128 * 64];
    __shared__ bf16 Bs[2][128 * 64];
    __shared__ float Zs[2][128];
    const int tid = threadIdx.x, wid = tid >> 6, lane = tid & 63;
    const int wm = wid >> 1, wn = wid & 1;
    const int i0 = blockIdx.x * 128;
    const int h = blockIdx.y & 15, b = blockIdx.y >> 4;
    const int q = lane >> 4, lm = lane & 15;

    const bf16* Qh = Qb + ((size_t)(b * 1024 + i0)) * 1024 + h * 64;
    const bf16* Kh = Kb + ((size_t)(b * 1024)) * 1024 + h * 64;

    stage128x64(Qh, 1024, As, tid);
    stage128x64(Kh, 1024, Bs[0], tid);

    float rs[4][4];
#pragma unroll
    for (int i = 0; i < 4; ++i)
#pragma unroll
        for (int r = 0; r < 4; ++r) rs[i][r] = 0.f;

    for (int jt = 0; jt < 8; ++jt) {
        __syncthreads();   // Bs[jt&1] staged; all waves done reading Bs[(jt+1)&1]
        if (jt < 7)
            stage128x64(Kh + (size_t)(jt + 1) * 128 * 1024, 1024, Bs[(jt + 1) & 1], tid);

        f32x4 acc[4][4];
        const f32x4 z4 = {0.f, 0.f, 0.f, 0.f};
#pragma unroll
        for (int i = 0; i < 4; ++i)
#pragma unroll
            for (int j = 0; j < 4; ++j) acc[i][j] = z4;
        mma_tile(As, Bs[jt & 1], wm, wn, lane, acc);

#pragma unroll
        for (int i = 0; i < 4; ++i)
#pragma unroll
            for (int r = 0; r < 4; ++r) {
                const int ii = i0 + wm * 64 + i * 16 + q * 4 + r;
                const size_t mrow = (size_t)b * 16384 + (size_t)ii * 16 + h;
#pragma unroll
                for (int j = 0; j < 4; ++j) {
                    const int jj = jt * 128 + wn * 64 + j * 16 + lm;
                    const float s = acc[i][j][r] * 0.125f;
                    const int mk = mask[((size_t)b * 1024 + ii) * 1024 + jj];
                    const float p = mk ? __expf(s) : 0.f;
                    Pun[mrow * 1024 + jj] = f2bf(p);
                    rs[i][r] += p;
                }
            }
    }

#pragma unroll
    for (int i = 0; i < 4; ++i)
#pragma unroll
        for (int r = 0; r < 4; ++r) {
            float v = rs[i][r];
            for (int off = 1; off < 16; off <<= 1) v += __shfl_xor(v, off, 16);
            if (lm == 0) Zs[wn][wm * 64 + i * 16 + q * 4 + r] = v;
        }
    __syncthreads();
    if (tid < 128) {
        const size_t m = (size_t)b * 16384 + (size_t)(i0 + tid) * 16 + h;
        Z[m] = Zs[0][tid] + Zs[1][tid];
    }
}

// out = (Pun @ Wo^T) / Z[m] + bo[e].  M=65536, N=1024, K=1024.
//
// R5: deepen the pipeline. R4's 8-phase gated vmcnt(2) — the newest retired
// load was issued only ~1 phase (~200cy) before the wait, vs ~900cy HBM
// latency; with 1 block/CU every gate exposed ~600cy of stall (MfmaUtil
// stuck at 30%). Fix: read ALL 8 B-frags (both ks) at P0/P4 so B halves
// free after P0/P4; stage each half at its earliest-free slot:
//   P0: A1(t+1)   [buf1.A1 free after prev P7; read P5  -> dist 5]
//   P1: B0,B1(t+2)[buf0.B  free after P0;      read P0' -> dist 7]
//   P3: A0(t+2)   [buf0.A0 free after P2;      read P0' -> dist 5]
//   P4: A1(t+2)   [buf0.A1 free after P3;      read P1' -> dist 5]
//   P5: B0,B1(t+3)[buf1.B  free after P4;      read P4' -> dist 7]
//   P7: A0(t+3)   [buf1.A0 free after P6;      read P4' -> dist 5]
// Gates: vmcnt(6) at end-P3 / end-P7 (14 loads outstanding, retire oldest
// 8 = exactly the next tile's 4 halves; newest retired was issued 4 phases
// (~800cy) back -> HBM latency covered; 3 stages stay in flight = m201's
// steady state). Tail t=14: suppress OOB stages, drain vmcnt(0) at end-P3.
__global__ __launch_bounds__(512, 2) void out_gemm_kernel(
        const bf16* __restrict__ Pun, const bf16* __restrict__ Wob,
        const float* __restrict__ Z, const float* __restrict__ bo,
        float* __restrict__ out) {
    __shared__ bf16 As[2][2][128 * 64];   // [buf][half][...]
    __shared__ bf16 Bs[2][2][128 * 64];
    const int tid = threadIdx.x, wid = tid >> 6, lane = tid & 63;
    const int wm = wid >> 2, wn = wid & 3;
    const int lm = lane & 15, g = lane >> 4;

    // XCD-disjoint decode: 1024 blocks = 8 XCDs x 32 m-tiles x 4 n-tiles
    const int bx = blockIdx.x, xcd = bx & 7, j = bx >> 3;
    const int m0 = (xcd * 32 + (j >> 2)) * 256;
    const int n0 = (j & 3) * 256;
    const bf16* Apan = Pun + (size_t)m0 * 1024;
    const bf16* Bpan = Wob + (size_t)n0 * 1024;

    f32x4 acc[8][4];
    const f32x4 z4 = {0.f, 0.f, 0.f, 0.f};
#pragma unroll
    for (int mi = 0; mi < 8; ++mi)
#pragma unroll
        for (int nj = 0; nj < 4; ++nj) acc[mi][nj] = z4;

    // prologue: tile0 complete + tile1 minus A1 (7 stages, 14 loads);
    // vmcnt(6) retires tile0's 8, keeps {B0(1),B1(1),A0(1)} in flight.
    stage_half512(Bpan,                   Bs[0][0], tid);
    stage_half512(Bpan + 128 * 1024,      Bs[0][1], tid);
    stage_half512(Apan,                   As[0][0], tid);
    stage_half512(Apan + 128 * 1024,      As[0][1], tid);
    stage_half512(Bpan + 64,              Bs[1][0], tid);
    stage_half512(Bpan + 128 * 1024 + 64, Bs[1][1], tid);
    stage_half512(Apan + 64,              As[1][0], tid);
    asm volatile("s_waitcnt vmcnt(6)" ::: "memory");
    __builtin_amdgcn_s_barrier();
    __builtin_amdgcn_sched_barrier(0);

    bf16x8 b[8];   // all B fragments (both ks), read at P0/P4, persist 4 phases

#define MFMA16(MH, KS)                                                        \
    _Pragma("unroll")                                                         \
    for (int mi = 0; mi < 4; ++mi)                                            \
      _Pragma("unroll")                                                       \
      for (int nj = 0; nj < 4; ++nj)                                          \
        acc[(MH) * 4 + mi][nj] = __builtin_amdgcn_mfma_f32_16x16x32_bf16(     \
            a[mi], b[(KS) * 4 + nj], acc[(MH) * 4 + mi][nj], 0, 0, 0);

#define PHASE(BUF, MH, KS, RB, STAGE, GATE)                                   \
  {                                                                           \
    const bf16* pA = &As[BUF][wm][((MH) * 64 + lm) * 64];                     \
    const int csk = (((KS) * 4 + g) ^ (lm & 7)) << 3;                         \
    bf16x8 a[4];                                                              \
    _Pragma("unroll")                                                         \
    for (int mi = 0; mi < 4; ++mi)                                            \
      a[mi] = *(const bf16x8*)(pA + mi * 16 * 64 + csk);                      \
    if (RB) {                                                                 \
      const bf16* pB = &Bs[BUF][wn >> 1][((wn & 1) * 64 + lm) * 64];          \
      _Pragma("unroll")                                                       \
      for (int k2 = 0; k2 < 2; ++k2) {                                        \
        const int cs2 = ((k2 * 4 + g) ^ (lm & 7)) << 3;                       \
        _Pragma("unroll")                                                     \
        for (int nj = 0; nj < 4; ++nj)                                        \
          b[k2 * 4 + nj] = *(const bf16x8*)(pB + nj * 16 * 64 + cs2);         \
      }                                                                       \
    }                                                                         \
    STAGE;                                                                    \
    __builtin_amdgcn_s_barrier();                                             \
    asm volatile("s_waitcnt lgkmcnt(0)" ::: "memory");                        \
    __builtin_amdgcn_sched_barrier(0);                                        \
    __builtin_amdgcn_s_setprio(1);                                            \
    MFMA16(MH, KS);                                                           \
    __builtin_amdgcn_s_setprio(0);                                            \
    __builtin_amdgcn_sched_barrier(0);                                        \
    GATE;                                                                     \
    __builtin_amdgcn_s_barrier();                                             \
    __builtin_amdgcn_sched_barrier(0);                                        \
  }

#pragma unroll 1
    for (int t = 0; t < 16; t += 2) {
        const bool more = (t < 14);   // tiles t+2 / t+3 exist
        // P0: tile t, MH0, ks0, read all B(buf0); stage A1(t+1)
        PHASE(0, 0, 0, true,
              stage_half512(Apan + 128 * 1024 + (t + 1) * 64, As[1][1], tid), )
        // P1: tile t, MH1, ks0; stage B0(t+2), B1(t+2)
        PHASE(0, 1, 0, false,
              if (more) { stage_half512(Bpan + (t + 2) * 64, Bs[0][0], tid);
                          stage_half512(Bpan + 128 * 1024 + (t + 2) * 64, Bs[0][1], tid); }, )
        // P2: tile t, MH0, ks1
        PHASE(0, 0, 1, false, , )
        // P3: tile t, MH1, ks1; stage A0(t+2); GATE -> tile t+1 ready
        PHASE(0, 1, 1, false,
              if (more) stage_half512(Apan + (t + 2) * 64, As[0][0], tid),
              if (more) { asm volatile("s_waitcnt vmcnt(6)" ::: "memory"); }
              else      { asm volatile("s_waitcnt vmcnt(0)" ::: "memory"); } )
        // P4: tile t+1, MH0, ks0, read all B(buf1); stage A1(t+2)
        PHASE(1, 0, 0, true,
              if (more) stage_half512(Apan + 128 * 1024 + (t + 2) * 64, As[0][1], tid), )
        // P5: tile t+1, MH1, ks0; stage B0(t+3), B1(t+3)
        PHASE(1, 1, 0, false,
              if (more) { stage_half512(Bpan + (t + 3) * 64, Bs[1][0], tid);
                          stage_half512(Bpan + 128 * 1024 + (t + 3) * 64, Bs[1][1], tid); }, )
        // P6: tile t+1, MH0, ks1
        PHASE(1, 0, 1, false, , )
        // P7: tile t+1, MH1, ks1; stage A0(t+3); GATE -> tile t+2 ready
        PHASE(1, 1, 1, false,
              if (more) stage_half512(Apan + (t + 3) * 64, As[1][0], tid),
              if (more) { asm volatile("s_waitcnt vmcnt(6)" ::: "memory"); } )
    }
#undef PHASE
#undef MFMA16

    // epilogue: acc -> out with 1/Z and bias (no LDS use, no sync needed)
#pragma unroll
    for (int mi = 0; mi < 8; ++mi) {
#pragma unroll
        for (int r = 0; r < 4; ++r) {
            const int row = m0 + wm * 128 + mi * 16 + g * 4 + r;
            const float zi = 1.0f / Z[row];
#pragma unroll
            for (int nj = 0; nj < 4; ++nj) {
                const int col = n0 + wn * 64 + nj * 16 + lm;
                out[(size_t)row * 1024 + col] = acc[mi][nj][r] * zi + bo[col];
            }
        }
    }
}

// ---------------------------------------------------------------- launch

extern "C" void kernel_launch(void* const* d_in, const int* in_sizes, int n_in,
                              void* d_out, int out_size, void* d_ws, size_t ws_size,
                              hipStream_t stream) {
    (void)in_sizes; (void)n_in; (void)out_size; (void)ws_size;
    const float* x    = (const float*)d_in[0];
    const int*   mask = (const int*)d_in[1];
    const float* Wq   = (const float*)d_in[2];
    const float* bq   = (const float*)d_in[3];
    const float* Wk   = (const float*)d_in[4];
    const float* bk   = (const float*)d_in[5];
    // d_in[6]=Wv, d_in[7]=bv: computed-then-discarded in reference; skipped.
    const float* Wo   = (const float*)d_in[8];
    const float* bo   = (const float*)d_in[9];

    char* ws = (char*)d_ws;
    bf16*  xb  = (bf16*)(ws);                    //  8 MB  x bf16
    bf16*  Wqb = (bf16*)(ws + 8388608);          //  2 MB
    bf16*  Wkb = (bf16*)(ws + 10485760);         //  2 MB
    bf16*  Wob = (bf16*)(ws + 12582912);         //  2 MB
    bf16*  Qb  = (bf16*)(ws + 14680064);         //  8 MB
    bf16*  Kb  = (bf16*)(ws + 23068672);         //  8 MB
    float* Z   = (float*)(ws + 31457280);        // 256 KB
    bf16*  Pun = (bf16*)(ws + 31981568);         // 128 MB (end ~158.5 MB)

    convert_kernel<<<7168, 256, 0, stream>>>(x, Wq, Wk, Wo,
        (unsigned short*)xb, (unsigned short*)Wqb, (unsigned short*)Wkb,
        (unsigned short*)Wob);
    proj_kernel<<<dim3(8, 32, 2), 256, 0, stream>>>(xb, Wqb, Wkb, bq, bk,
        (unsigned short*)Qb, (unsigned short*)Kb);
    scores_kernel<<<dim3(8, 64), 256, 0, stream>>>(Qb, Kb, mask,
        (unsigned short*)Pun, Z);
    out_gemm_kernel<<<1024, 512, 0, stream>>>(Pun, Wob, Z, bo, (float*)d_out);
}

// Round 5
// 523.989 us; speedup vs baseline: 1.2436x; 1.0418x over previous
//
#include <hip/hip_runtime.h>

typedef __bf16 bf16;
typedef __attribute__((ext_vector_type(8))) __bf16 bf16x8;
typedef __attribute__((ext_vector_type(4))) float f32x4;

// ---------------------------------------------------------------- utilities

__device__ __forceinline__ unsigned short f2bf(float f) {
    union { float f; unsigned u; } v; v.f = f;
    unsigned r = v.u + 0x7FFFu + ((v.u >> 16) & 1u);   // RNE
    return (unsigned short)(r >> 16);
}

// Stage a 128-row x 64-bf16 (128 B/row) tile from global into LDS via
// global_load_lds width=16. 256 threads x 4 reps x 16 B = 16 KB.
// XOR swizzle: row r's global 16B chunk c lands at LDS chunk c ^ (r&7).
__device__ __forceinline__ void stage128x64(const bf16* g, int ld_elems,
                                            bf16* lds, int tid) {
    const char* gb = (const char*)g;
    const int ldb = ld_elems * 2;
#pragma unroll
    for (int r = 0; r < 4; ++r) {
        int lin = r * 256 + tid;          // 0..1023, lane-contiguous per wave
        int row = lin >> 3;               // 8 x 16B chunks per 128 B row
        int ch  = (lin & 7) ^ (row & 7);  // XOR swizzle
        __builtin_amdgcn_global_load_lds(
            (const __attribute__((address_space(1))) void*)(gb + (size_t)row * ldb + ch * 16),
            (__attribute__((address_space(3))) void*)(lds + lin * 8),
            16, 0, 0);
    }
}

// Same tile shape, 512-thread block variant (2 loads/thread).
// Row stride hardcoded 1024 elems (both Pun and Wob).
__device__ __forceinline__ void stage_half512(const bf16* g, bf16* lds, int tid) {
    const char* gb = (const char*)g;
#pragma unroll
    for (int r = 0; r < 2; ++r) {
        int lin = r * 512 + tid;          // 0..1023
        int row = lin >> 3;
        int ch  = (lin & 7) ^ (row & 7);
        __builtin_amdgcn_global_load_lds(
            (const __attribute__((address_space(1))) void*)(gb + (size_t)row * 2048 + ch * 16),
            (__attribute__((address_space(3))) void*)(lds + lin * 8),
            16, 0, 0);
    }
}

// 128x128 tile step (4 waves 2x2), BK=64. Used by proj and scores.
__device__ __forceinline__ void mma_tile(const bf16* As, const bf16* Bs,
                                         int wm, int wn, int lane,
                                         f32x4 acc[4][4]) {
    const int lm = lane & 15;
    const int g  = lane >> 4;
#pragma unroll
    for (int ks = 0; ks < 2; ++ks) {
        const int c = ks * 4 + g;
        bf16x8 a[4], b[4];
#pragma unroll
        for (int t = 0; t < 4; ++t) {
            const int row = wm * 64 + t * 16 + lm;
            a[t] = *(const bf16x8*)(As + row * 64 + ((c ^ (row & 7)) << 3));
        }
#pragma unroll
        for (int t = 0; t < 4; ++t) {
            const int row = wn * 64 + t * 16 + lm;
            b[t] = *(const bf16x8*)(Bs + row * 64 + ((c ^ (row & 7)) << 3));
        }
#pragma unroll
        for (int i = 0; i < 4; ++i)
#pragma unroll
            for (int j = 0; j < 4; ++j)
                acc[i][j] = __builtin_amdgcn_mfma_f32_16x16x32_bf16(a[i], b[j], acc[i][j], 0, 0, 0);
    }
}

// ---------------------------------------------------------------- kernels

// fp32 -> bf16 for x, Wq, Wk, Wo.
__global__ void convert_kernel(const float* __restrict__ x,  const float* __restrict__ Wq,
                               const float* __restrict__ Wk, const float* __restrict__ Wo,
                               unsigned short* xb, unsigned short* Wqb,
                               unsigned short* Wkb, unsigned short* Wob) {
    size_t i = ((size_t)blockIdx.x * 256 + threadIdx.x) * 4;
    const float* src; unsigned short* dst; size_t off;
    if      (i < 4194304) { src = x;  dst = xb;  off = i; }
    else if (i < 5242880) { src = Wq; dst = Wqb; off = i - 4194304; }
    else if (i < 6291456) { src = Wk; dst = Wkb; off = i - 5242880; }
    else                  { src = Wo; dst = Wob; off = i - 6291456; }
    float4 v = *(const float4*)(src + off);
    ushort4 o;
    o.x = f2bf(v.x); o.y = f2bf(v.y); o.z = f2bf(v.z); o.w = f2bf(v.w);
    *(ushort4*)(dst + off) = o;
}

// R5: pack mask (int32 0/1) into bits: word w = bits for elements w*64..w*64+63.
// Runs AFTER proj (output aliases the then-dead Wqb buffer). ~0.5 MB output,
// L2-resident for scores (vs 16.8 MB int32 scalar-loaded per element before).
__global__ void maskpack_kernel(const int* __restrict__ mask,
                                unsigned long long* __restrict__ mw) {
    const int gid = blockIdx.x * 256 + threadIdx.x;
    const unsigned long long bal = __ballot(mask[gid] != 0);
    if ((threadIdx.x & 63) == 0) mw[gid >> 6] = bal;
}

// Q = Xb @ Wq^T + bq, K = Xb @ Wk^T + bk  (blockIdx.z selects Q or K).
__global__ __launch_bounds__(256) void proj_kernel(
        const bf16* __restrict__ X, const bf16* __restrict__ Wqb,
        const bf16* __restrict__ Wkb, const float* __restrict__ bq,
        const float* __restrict__ bk, unsigned short* Qb, unsigned short* Kb) {
    __shared__ bf16 As[128 * 64];
    __shared__ bf16 Bs[128 * 64];
    const int tid = threadIdx.x, wid = tid >> 6, lane = tid & 63;
    const int wm = wid >> 1, wn = wid & 1;
    const int n0 = blockIdx.x * 128, m0 = blockIdx.y * 128;
    const bf16*  W    = blockIdx.z ? Wkb : Wqb;
    const float* bias = blockIdx.z ? bk  : bq;
    unsigned short* Out = blockIdx.z ? Kb : Qb;

    f32x4 acc[4][4];
    const f32x4 z4 = {0.f, 0.f, 0.f, 0.f};
#pragma unroll
    for (int i = 0; i < 4; ++i)
#pragma unroll
        for (int j = 0; j < 4; ++j) acc[i][j] = z4;

    for (int kt = 0; kt < 16; ++kt) {
        stage128x64(X + (size_t)m0 * 1024 + kt * 64, 1024, As, tid);
        stage128x64(W + (size_t)n0 * 1024 + kt * 64, 1024, Bs, tid);
        __syncthreads();
        mma_tile(As, Bs, wm, wn, lane, acc);
        __syncthreads();
    }

    const int q = lane >> 4, lm = lane & 15;
#pragma unroll
    for (int j = 0; j < 4; ++j) {
        const int col = n0 + wn * 64 + j * 16 + lm;
        const float bc = bias[col];
#pragma unroll
        for (int i = 0; i < 4; ++i)
#pragma unroll
            for (int r = 0; r < 4; ++r) {
                const int row = m0 + wm * 64 + i * 16 + q * 4 + r;
                Out[(size_t)row * 1024 + col] = f2bf(acc[i][j][r] + bc);
            }
    }
}

// One block per (b, h, 128-row i-tile). Sweeps all 1024 keys in 8 chunks of
// 128 with a double-buffered K-tile. Q-tile staged ONCE.
//
// R5 epilogue rework (old: per element {scalar int mask load, expf, 2-B
// global store} -> 64 loads + 256 scattered store-instrs per wave per jt):
//  (a) mask from bit-packed words: one 8-B broadcast load per (i,r) covers
//      all 4 j (bit = j*16+lm) -> 16 loads/thread/jt, traffic 16.8->0.5 MB.
//  (b) P bounced through LDS (Pl[2][64][128], one 16 KB half per wm-group
//      round), then swept to Pun with full-line dwordx4 stores: global
//      store instrs 256 -> 8 per jt, perfectly coalesced.
//  Zs overlays Pl[0] (disjoint lifetime: Zs written after the jt-7 half-1
//  barrier which orders it after every Pl[0] sweep read). LDS total 80 KB
//  -> still 2 blocks/CU. Barriers: pack half -> sync -> sweep half (x2);
//  Pl[x] writer/reader pairs all separated by >=1 barrier (audited).
__global__ __launch_bounds__(256) void scores_kernel(
        const bf16* __restrict__ Qb, const bf16* __restrict__ Kb,
        const unsigned long long* __restrict__ maskw,
        unsigned short* Pun, float* Z) {
    __shared__ bf16 As[128 * 64];
    __shared__ bf16 Bs[2][128 * 64];
    __shared__ __align__(16) unsigned short Pl[2][64][128];   // 32 KB
    float (*Zs)[128] = (float (*)[128])(&Pl[0][0][0]);        // overlay
    const int tid = threadIdx.x, wid = tid >> 6, lane = tid & 63;
    const int wm = wid >> 1, wn = wid & 1;
    const int i0 = blockIdx.x * 128;
    const int h = blockIdx.y & 15, b = blockIdx.y >> 4;
    const int q = lane >> 4, lm = lane & 15;

    const bf16* Qh = Qb + ((size_t)(b * 1024 + i0)) * 1024 + h * 64;
    const bf16* Kh = Kb + ((size_t)(b * 1024)) * 1024 + h * 64;

    stage128x64(Qh, 1024, As, tid);
    stage128x64(Kh, 1024, Bs[0], tid);

    float rs[4][4];
#pragma unroll
    for (int i = 0; i < 4; ++i)
#pragma unroll
        for (int r = 0; r < 4; ++r) rs[i][r] = 0.f;

    for (int jt = 0; jt < 8; ++jt) {
        __syncthreads();   // Bs[jt&1] staged; everyone done with Bs[(jt+1)&1] and Pl
        if (jt < 7)
            stage128x64(Kh + (size_t)(jt + 1) * 128 * 1024, 1024, Bs[(jt + 1) & 1], tid);

        f32x4 acc[4][4];
        const f32x4 z4 = {0.f, 0.f, 0.f, 0.f};
#pragma unroll
        for (int i = 0; i < 4; ++i)
#pragma unroll
            for (int j = 0; j < 4; ++j) acc[i][j] = z4;
        mma_tile(As, Bs[jt & 1], wm, wn, lane, acc);

#pragma unroll
        for (int half = 0; half < 2; ++half) {
            if (wm == half) {   // wave-uniform predicate; barriers stay outside
#pragma unroll
                for (int i = 0; i < 4; ++i)
#pragma unroll
                    for (int r = 0; r < 4; ++r) {
                        const int lrow = i * 16 + q * 4 + r;
                        const int ii = i0 + half * 64 + lrow;
                        const unsigned long long W =
                            maskw[(size_t)(b * 1024 + ii) * 16 + jt * 2 + wn];
                        const unsigned lo = (unsigned)W, hi = (unsigned)(W >> 32);
#pragma unroll
                        for (int j = 0; j < 4; ++j) {
                            const unsigned mb =
                                (((j & 2) ? hi : lo) >> (((j & 1) << 4) + lm)) & 1u;
                            const float s = acc[i][j][r] * 0.125f;
                            const float p = mb ? __expf(s) : 0.f;
                            rs[i][r] += p;
                            Pl[half][lrow][wn * 64 + j * 16 + lm] = f2bf(p);
                        }
                    }
            }
            __syncthreads();   // Pl[half] packed; sweep it with all 256 threads
#pragma unroll
            for (int pass = 0; pass < 4; ++pass) {
                const int chunk = pass * 256 + tid;     // 0..1023
                const int row = chunk >> 4, c16 = chunk & 15;
                const size_t mrow =
                    (size_t)b * 16384 + (size_t)(i0 + half * 64 + row) * 16 + h;
                *(bf16x8*)(Pun + mrow * 1024 + jt * 128 + c16 * 8) =
                    *(const bf16x8*)(&Pl[half][row][c16 * 8]);
            }
            // no barrier needed here: half-1 pack writes Pl[1] (disjoint from
            // sweep-0's Pl[0] reads); next-jt pack-0 is gated by the top sync.
        }
    }

    // reduce row sums: 16 lanes -> wn pair via Zs (overlaying Pl[0]; ordered
    // after all Pl[0] sweep reads by the jt=7 half-1 barrier) -> global Z
#pragma unroll
    for (int i = 0; i < 4; ++i)
#pragma unroll
        for (int r = 0; r < 4; ++r) {
            float v = rs[i][r];
            for (int off = 1; off < 16; off <<= 1) v += __shfl_xor(v, off, 16);
            if (lm == 0) Zs[wn][wm * 64 + i * 16 + q * 4 + r] = v;
        }
    __syncthreads();
    if (tid < 128) {
        const size_t m = (size_t)b * 16384 + (size_t)(i0 + tid) * 16 + h;
        Z[m] = Zs[0][tid] + Zs[1][tid];
    }
}

// out = (Pun @ Wo^T) / Z[m] + bo[e].  M=65536, N=1024, K=1024.
// R4 8-phase 256x256 schedule, deep-prefetch variant (unchanged in R5):
// all-B-frag read at P0/P4, stages at earliest-free slots, vmcnt(6) gates
// at end-P3/P7 (issue->gate distance >=4 phases).
__global__ __launch_bounds__(512, 2) void out_gemm_kernel(
        const bf16* __restrict__ Pun, const bf16* __restrict__ Wob,
        const float* __restrict__ Z, const float* __restrict__ bo,
        float* __restrict__ out) {
    __shared__ bf16 As[2][2][128 * 64];   // [buf][half][...]
    __shared__ bf16 Bs[2][2][128 * 64];
    const int tid = threadIdx.x, wid = tid >> 6, lane = tid & 63;
    const int wm = wid >> 2, wn = wid & 3;
    const int lm = lane & 15, g = lane >> 4;

    // XCD-disjoint decode: 1024 blocks = 8 XCDs x 32 m-tiles x 4 n-tiles
    const int bx = blockIdx.x, xcd = bx & 7, j = bx >> 3;
    const int m0 = (xcd * 32 + (j >> 2)) * 256;
    const int n0 = (j & 3) * 256;
    const bf16* Apan = Pun + (size_t)m0 * 1024;
    const bf16* Bpan = Wob + (size_t)n0 * 1024;

    f32x4 acc[8][4];
    const f32x4 z4 = {0.f, 0.f, 0.f, 0.f};
#pragma unroll
    for (int mi = 0; mi < 8; ++mi)
#pragma unroll
        for (int nj = 0; nj < 4; ++nj) acc[mi][nj] = z4;

    // prologue: tile0 complete + tile1 minus A1 (7 stages, 14 loads);
    // vmcnt(6) retires tile0's 8, keeps {B0(1),B1(1),A0(1)} in flight.
    stage_half512(Bpan,                   Bs[0][0], tid);
    stage_half512(Bpan + 128 * 1024,      Bs[0][1], tid);
    stage_half512(Apan,                   As[0][0], tid);
    stage_half512(Apan + 128 * 1024,      As[0][1], tid);
    stage_half512(Bpan + 64,              Bs[1][0], tid);
    stage_half512(Bpan + 128 * 1024 + 64, Bs[1][1], tid);
    stage_half512(Apan + 64,              As[1][0], tid);
    asm volatile("s_waitcnt vmcnt(6)" ::: "memory");
    __builtin_amdgcn_s_barrier();
    __builtin_amdgcn_sched_barrier(0);

    bf16x8 b[8];   // all B fragments (both ks), read at P0/P4, persist 4 phases

#define MFMA16(MH, KS)                                                        \
    _Pragma("unroll")                                                         \
    for (int mi = 0; mi < 4; ++mi)                                            \
      _Pragma("unroll")                                                       \
      for (int nj = 0; nj < 4; ++nj)                                          \
        acc[(MH) * 4 + mi][nj] = __builtin_amdgcn_mfma_f32_16x16x32_bf16(     \
            a[mi], b[(KS) * 4 + nj], acc[(MH) * 4 + mi][nj], 0, 0, 0);

#define PHASE(BUF, MH, KS, RB, STAGE, GATE)                                   \
  {                                                                           \
    const bf16* pA = &As[BUF][wm][((MH) * 64 + lm) * 64];                     \
    const int csk = (((KS) * 4 + g) ^ (lm & 7)) << 3;                         \
    bf16x8 a[4];                                                              \
    _Pragma("unroll")                                                         \
    for (int mi = 0; mi < 4; ++mi)                                            \
      a[mi] = *(const bf16x8*)(pA + mi * 16 * 64 + csk);                      \
    if (RB) {                                                                 \
      const bf16* pB = &Bs[BUF][wn >> 1][((wn & 1) * 64 + lm) * 64];          \
      _Pragma("unroll")                                                       \
      for (int k2 = 0; k2 < 2; ++k2) {                                        \
        const int cs2 = ((k2 * 4 + g) ^ (lm & 7)) << 3;                       \
        _Pragma("unroll")                                                     \
        for (int nj = 0; nj < 4; ++nj)                                        \
          b[k2 * 4 + nj] = *(const bf16x8*)(pB + nj * 16 * 64 + cs2);         \
      }                                                                       \
    }                                                                         \
    STAGE;                                                                    \
    __builtin_amdgcn_s_barrier();                                             \
    asm volatile("s_waitcnt lgkmcnt(0)" ::: "memory");                        \
    __builtin_amdgcn_sched_barrier(0);                                        \
    __builtin_amdgcn_s_setprio(1);                                            \
    MFMA16(MH, KS);                                                           \
    __builtin_amdgcn_s_setprio(0);                                            \
    __builtin_amdgcn_sched_barrier(0);                                        \
    GATE;                                                                     \
    __builtin_amdgcn_s_barrier();                                             \
    __builtin_amdgcn_sched_barrier(0);                                        \
  }

#pragma unroll 1
    for (int t = 0; t < 16; t += 2) {
        const bool more = (t < 14);   // tiles t+2 / t+3 exist
        // P0: tile t, MH0, ks0, read all B(buf0); stage A1(t+1)
        PHASE(0, 0, 0, true,
              stage_half512(Apan + 128 * 1024 + (t + 1) * 64, As[1][1], tid), )
        // P1: tile t, MH1, ks0; stage B0(t+2), B1(t+2)
        PHASE(0, 1, 0, false,
              if (more) { stage_half512(Bpan + (t + 2) * 64, Bs[0][0], tid);
                          stage_half512(Bpan + 128 * 1024 + (t + 2) * 64, Bs[0][1], tid); }, )
        // P2: tile t, MH0, ks1
        PHASE(0, 0, 1, false, , )
        // P3: tile t, MH1, ks1; stage A0(t+2); GATE -> tile t+1 ready
        PHASE(0, 1, 1, false,
              if (more) stage_half512(Apan + (t + 2) * 64, As[0][0], tid),
              if (more) { asm volatile("s_waitcnt vmcnt(6)" ::: "memory"); }
              else      { asm volatile("s_waitcnt vmcnt(0)" ::: "memory"); } )
        // P4: tile t+1, MH0, ks0, read all B(buf1); stage A1(t+2)
        PHASE(1, 0, 0, true,
              if (more) stage_half512(Apan + 128 * 1024 + (t + 2) * 64, As[0][1], tid), )
        // P5: tile t+1, MH1, ks0; stage B0(t+3), B1(t+3)
        PHASE(1, 1, 0, false,
              if (more) { stage_half512(Bpan + (t + 3) * 64, Bs[1][0], tid);
                          stage_half512(Bpan + 128 * 1024 + (t + 3) * 64, Bs[1][1], tid); }, )
        // P6: tile t+1, MH0, ks1
        PHASE(1, 0, 1, false, , )
        // P7: tile t+1, MH1, ks1; stage A0(t+3); GATE -> tile t+2 ready
        PHASE(1, 1, 1, false,
              if (more) stage_half512(Apan + (t + 3) * 64, As[1][0], tid),
              if (more) { asm volatile("s_waitcnt vmcnt(6)" ::: "memory"); } )
    }
#undef PHASE
#undef MFMA16

    // epilogue: acc -> out with 1/Z and bias (no LDS use, no sync needed)
#pragma unroll
    for (int mi = 0; mi < 8; ++mi) {
#pragma unroll
        for (int r = 0; r < 4; ++r) {
            const int row = m0 + wm * 128 + mi * 16 + g * 4 + r;
            const float zi = 1.0f / Z[row];
#pragma unroll
            for (int nj = 0; nj < 4; ++nj) {
                const int col = n0 + wn * 64 + nj * 16 + lm;
                out[(size_t)row * 1024 + col] = acc[mi][nj][r] * zi + bo[col];
            }
        }
    }
}

// ---------------------------------------------------------------- launch

extern "C" void kernel_launch(void* const* d_in, const int* in_sizes, int n_in,
                              void* d_out, int out_size, void* d_ws, size_t ws_size,
                              hipStream_t stream) {
    (void)in_sizes; (void)n_in; (void)out_size; (void)ws_size;
    const float* x    = (const float*)d_in[0];
    const int*   mask = (const int*)d_in[1];
    const float* Wq   = (const float*)d_in[2];
    const float* bq   = (const float*)d_in[3];
    const float* Wk   = (const float*)d_in[4];
    const float* bk   = (const float*)d_in[5];
    // d_in[6]=Wv, d_in[7]=bv: computed-then-discarded in reference; skipped.
    const float* Wo   = (const float*)d_in[8];
    const float* bo   = (const float*)d_in[9];

    char* ws = (char*)d_ws;
    bf16*  xb  = (bf16*)(ws);                    //  8 MB  x bf16
    bf16*  Wqb = (bf16*)(ws + 8388608);          //  2 MB
    bf16*  Wkb = (bf16*)(ws + 10485760);         //  2 MB
    bf16*  Wob = (bf16*)(ws + 12582912);         //  2 MB
    bf16*  Qb  = (bf16*)(ws + 14680064);         //  8 MB
    bf16*  Kb  = (bf16*)(ws + 23068672);         //  8 MB
    float* Z   = (float*)(ws + 31457280);        // 256 KB
    bf16*  Pun = (bf16*)(ws + 31981568);         // 128 MB (end ~158.5 MB)
    // packed mask bits (512 KB) ALIAS the Wqb region — Wqb is dead after
    // proj_kernel; maskpack launches after proj on the same stream.
    unsigned long long* maskw = (unsigned long long*)(ws + 8388608);

    convert_kernel<<<7168, 256, 0, stream>>>(x, Wq, Wk, Wo,
        (unsigned short*)xb, (unsigned short*)Wqb, (unsigned short*)Wkb,
        (unsigned short*)Wob);
    proj_kernel<<<dim3(8, 32, 2), 256, 0, stream>>>(xb, Wqb, Wkb, bq, bk,
        (unsigned short*)Qb, (unsigned short*)Kb);
    maskpack_kernel<<<16384, 256, 0, stream>>>(mask, maskw);
    scores_kernel<<<dim3(8, 64), 256, 0, stream>>>(Qb, Kb, maskw,
        (unsigned short*)Pun, Z);
    out_gemm_kernel<<<1024, 512, 0, stream>>>(Pun, Wob, Z, bo, (float*)d_out);
}